// Round 3
// baseline (1746.337 us; speedup 1.0000x reference)
//
#include <hip/hip_runtime.h>

// Problem constants (from reference setup_inputs)
#define N_NODES  200000
#define N_EDGES  6400000
#define NGRAPH   128
#define H        32

// Bucketed aggregation parameters
#define BNODES   512                      // dst nodes per bucket (9 bits)
#define NBUCK    391                      // ceil(200000/512); last bucket has 320 nodes
#define P_BLOCKS 256                      // partition blocks
#define EPB      25000                    // edges per partition block (256*25000 = 6.4M)

// ---------------------------------------------------------------------------
// K0: h_global_graph = relu(x_global @ W_global + b_global)   [128, 32]
// ---------------------------------------------------------------------------
__global__ void k_global_enc(const float* __restrict__ xg,
                             const float* __restrict__ Wg,
                             const float* __restrict__ bg,
                             float* __restrict__ hg) {
    int tid = blockIdx.x * blockDim.x + threadIdx.x;
    if (tid >= NGRAPH * H) return;
    int b = tid >> 5, t = tid & 31;
    float acc = bg[t];
#pragma unroll
    for (int k = 0; k < 8; ++k)
        acc = fmaf(xg[b * 8 + k], Wg[k * H + t], acc);
    hg[tid] = fmaxf(acc, 0.f);
}

// ---------------------------------------------------------------------------
// K1: per-node encoder. 32 threads per node.
// m[n] = relu(h0 @ W_msg + b_msg)   (per-source message == self-loop msg)
// s[n] = h0 @ W_self + b_self       (pre-relu self path)
// ---------------------------------------------------------------------------
__global__ void k_node_enc(const float* __restrict__ xl,
                           const int*   __restrict__ batch,
                           const float* __restrict__ hg,
                           const float* __restrict__ Wl,   const float* __restrict__ bl,
                           const float* __restrict__ Wmix, const float* __restrict__ bmix,
                           const float* __restrict__ Wmsg, const float* __restrict__ bmsg,
                           const float* __restrict__ Wself,const float* __restrict__ bself,
                           float* __restrict__ m, float* __restrict__ s) {
    __shared__ float hcat[8][96];
    __shared__ float h0s[8][32];

    int tid   = threadIdx.x;
    int local = tid >> 5;
    int t     = tid & 31;
    int n     = blockIdx.x * 8 + local;   // 25000 blocks * 8 == 200000 exactly

    float hl = bl[t];
#pragma unroll
    for (int k = 0; k < 16; ++k)
        hl = fmaf(xl[n * 16 + k], Wl[k * H + t], hl);
    hl = fmaxf(hl, 0.f);

    float hgv = hg[batch[n] * H + t];

    hcat[local][t]      = hl;
    hcat[local][32 + t] = hgv;
    hcat[local][64 + t] = hl * hgv;
    __syncthreads();

    float h0 = bmix[t];
#pragma unroll
    for (int k = 0; k < 96; ++k)
        h0 = fmaf(hcat[local][k], Wmix[k * H + t], h0);
    h0 = fmaxf(h0, 0.f);
    h0s[local][t] = h0;
    __syncthreads();

    float mv = bmsg[t], sv = bself[t];
#pragma unroll
    for (int k = 0; k < 32; ++k) {
        float hv = h0s[local][k];
        mv = fmaf(hv, Wmsg[k * H + t], mv);
        sv = fmaf(hv, Wself[k * H + t], sv);
    }
    m[n * H + t] = fmaxf(mv, 0.f);
    s[n * H + t] = sv;
}

// ---------------------------------------------------------------------------
// Partition pass 1: per-(block,bucket) histogram.  gcnt[bucket*P + blk]
// ---------------------------------------------------------------------------
__global__ void k_pcount(const int* __restrict__ ei, int* __restrict__ gcnt) {
    __shared__ int cnt[NBUCK];
    int t = threadIdx.x, blk = blockIdx.x;
    for (int i = t; i < NBUCK; i += 256) cnt[i] = 0;
    __syncthreads();
    int e1 = (blk + 1) * EPB;
    for (int e = blk * EPB + t; e < e1; e += 256)
        atomicAdd(&cnt[ei[N_EDGES + e] >> 9], 1);
    __syncthreads();
    for (int i = t; i < NBUCK; i += 256)
        gcnt[i * P_BLOCKS + blk] = cnt[i];
}

// ---------------------------------------------------------------------------
// Scan of gcnt (NBUCK*P_BLOCKS = 100096 ints, bucket-major) -> exclusive offsets
// ---------------------------------------------------------------------------
__global__ void k_blocksum_g(const int* __restrict__ gcnt, int* __restrict__ bsum) {
    int b = blockIdx.x, t = threadIdx.x;
    int v = gcnt[b * 256 + t];
#pragma unroll
    for (int off = 32; off >= 1; off >>= 1)
        v += __shfl_down(v, off, 64);
    __shared__ int w4[4];
    if ((t & 63) == 0) w4[t >> 6] = v;
    __syncthreads();
    if (t == 0) bsum[b] = w4[0] + w4[1] + w4[2] + w4[3];
}

__global__ void k_scan_bsums_g(const int* __restrict__ bsum, int* __restrict__ boff) {
    __shared__ int sd[1024];
    int t = threadIdx.x;
    sd[t] = (t < NBUCK) ? bsum[t] : 0;
    __syncthreads();
#pragma unroll
    for (int off = 1; off < 1024; off <<= 1) {
        int v = (t >= off) ? sd[t - off] : 0;
        __syncthreads();
        sd[t] += v;
        __syncthreads();
    }
    if (t < NBUCK) boff[t] = (t == 0) ? 0 : sd[t - 1];
}

// in-place: gcnt -> exclusive global offset of each (bucket, block) region
__global__ void k_make_cursor_g(int* __restrict__ gcnt, const int* __restrict__ boff) {
    __shared__ int sd[256];
    int b = blockIdx.x, t = threadIdx.x, i = b * 256 + t;
    int c = gcnt[i];
    sd[t] = c;
    __syncthreads();
#pragma unroll
    for (int off = 1; off < 256; off <<= 1) {
        int v = (t >= off) ? sd[t - off] : 0;
        __syncthreads();
        sd[t] += v;
        __syncthreads();
    }
    gcnt[i] = boff[b] + sd[t] - c;
}

// ---------------------------------------------------------------------------
// Partition pass 2: scatter packed edges into bucket-grouped ebuf.
// Each (block,bucket) writes a private contiguous region (~64 entries = 256 B)
// -> write locality; LDS atomics only.
// ---------------------------------------------------------------------------
__global__ void k_pscatter(const int* __restrict__ ei, const int* __restrict__ goff,
                           unsigned int* __restrict__ ebuf) {
    __shared__ int cur[NBUCK];
    int t = threadIdx.x, blk = blockIdx.x;
    for (int i = t; i < NBUCK; i += 256) cur[i] = goff[i * P_BLOCKS + blk];
    __syncthreads();
    int e1 = (blk + 1) * EPB;
    for (int e = blk * EPB + t; e < e1; e += 256) {
        unsigned src = (unsigned)ei[e];
        int dst = ei[N_EDGES + e];
        int pos = atomicAdd(&cur[dst >> 9], 1);
        ebuf[pos] = (src << 9) | (unsigned)(dst & 511);
    }
}

// ---------------------------------------------------------------------------
// K-aggr: one block per bucket. 64 KB LDS accumulator [512 nodes x 32 feats].
// 32-lane groups: gather m[src] (coalesced 128B), LDS atomicAdd into acc.
// Fused final: h = relu(acc + m + s), 2-class head.
// ---------------------------------------------------------------------------
__global__ __launch_bounds__(256) void k_aggr(
        const int* __restrict__ goff,
        const unsigned int* __restrict__ ebuf,
        const float* __restrict__ m, const float* __restrict__ s,
        const float* __restrict__ Wout, const float* __restrict__ bout,
        float* __restrict__ out) {
    __shared__ float acc[BNODES * H];   // 64 KiB
    int t   = threadIdx.x & 31;
    int wid = threadIdx.x >> 5;         // 8 edge-groups
    int b   = blockIdx.x;

    for (int i = threadIdx.x; i < BNODES * H; i += 256) acc[i] = 0.f;
    __syncthreads();

    int start = goff[b * P_BLOCKS];
    int end   = (b == NBUCK - 1) ? N_EDGES : goff[(b + 1) * P_BLOCKS];

    // unroll-4: 4 independent gather chains per wave-half to hide LLC latency
    int j = start + wid;
    for (; j + 24 < end; j += 32) {
        unsigned p0 = ebuf[j];
        unsigned p1 = ebuf[j + 8];
        unsigned p2 = ebuf[j + 16];
        unsigned p3 = ebuf[j + 24];
        float v0 = m[(p0 >> 9) * H + t];
        float v1 = m[(p1 >> 9) * H + t];
        float v2 = m[(p2 >> 9) * H + t];
        float v3 = m[(p3 >> 9) * H + t];
        atomicAdd(&acc[(p0 & 511) * H + t], v0);
        atomicAdd(&acc[(p1 & 511) * H + t], v1);
        atomicAdd(&acc[(p2 & 511) * H + t], v2);
        atomicAdd(&acc[(p3 & 511) * H + t], v3);
    }
    for (; j < end; j += 8) {
        unsigned p = ebuf[j];
        atomicAdd(&acc[(p & 511) * H + t], m[(p >> 9) * H + t]);
    }
    __syncthreads();

    int nbase = b * BNODES;
    for (int nn = wid; nn < BNODES; nn += 8) {
        int n = nbase + nn;
        if (n >= N_NODES) break;
        int i = n * H + t;
        float h = fmaxf(acc[nn * H + t] + m[i] + s[i], 0.f);
        float p0 = h * Wout[t * 2 + 0];
        float p1 = h * Wout[t * 2 + 1];
#pragma unroll
        for (int off = 16; off >= 1; off >>= 1) {
            p0 += __shfl_down(p0, off, 32);
            p1 += __shfl_down(p1, off, 32);
        }
        if (t == 0) {
            out[n * 2 + 0] = p0 + bout[0];
            out[n * 2 + 1] = p1 + bout[1];
        }
    }
}

// ---------------------------------------------------------------------------
extern "C" void kernel_launch(void* const* d_in, const int* in_sizes, int n_in,
                              void* d_out, int out_size, void* d_ws, size_t ws_size,
                              hipStream_t stream) {
    const float* xl    = (const float*)d_in[0];
    const float* xg    = (const float*)d_in[1];
    const int*   batch = (const int*)  d_in[2];
    const int*   ei    = (const int*)  d_in[3];
    const float* Wl    = (const float*)d_in[4];
    const float* bl    = (const float*)d_in[5];
    const float* Wg    = (const float*)d_in[6];
    const float* bg    = (const float*)d_in[7];
    const float* Wmix  = (const float*)d_in[8];
    const float* bmix  = (const float*)d_in[9];
    const float* Wmsg  = (const float*)d_in[10];
    const float* bmsg  = (const float*)d_in[11];
    const float* Wself = (const float*)d_in[12];
    const float* bself = (const float*)d_in[13];
    const float* Wout  = (const float*)d_in[14];
    const float* bout  = (const float*)d_in[15];
    float* out = (float*)d_out;

    // Workspace layout:
    //   hg   [128*32]          f32
    //   m    [N*32]            f32
    //   s    [N*32]            f32
    //   gcnt [NBUCK*P_BLOCKS]  i32   (becomes region offsets in place)
    //   bsum [NBUCK]           i32
    //   boff [NBUCK]           i32
    //   ebuf [E]               u32   (packed (src<<9)|dstLocal, bucket-grouped)
    float* hg   = (float*)d_ws;
    float* m    = hg + NGRAPH * H;
    float* s    = m + (size_t)N_NODES * H;
    int*   gcnt = (int*)(s + (size_t)N_NODES * H);
    int*   bsum = gcnt + NBUCK * P_BLOCKS;
    int*   boff = bsum + NBUCK;
    unsigned int* ebuf = (unsigned int*)(boff + NBUCK);

    k_global_enc<<<(NGRAPH * H + 255) / 256, 256, 0, stream>>>(xg, Wg, bg, hg);

    k_node_enc<<<N_NODES / 8, 256, 0, stream>>>(xl, batch, hg,
                                                Wl, bl, Wmix, bmix,
                                                Wmsg, bmsg, Wself, bself,
                                                m, s);

    k_pcount<<<P_BLOCKS, 256, 0, stream>>>(ei, gcnt);
    k_blocksum_g<<<NBUCK, 256, 0, stream>>>(gcnt, bsum);
    k_scan_bsums_g<<<1, 1024, 0, stream>>>(bsum, boff);
    k_make_cursor_g<<<NBUCK, 256, 0, stream>>>(gcnt, boff);
    k_pscatter<<<P_BLOCKS, 256, 0, stream>>>(ei, gcnt, ebuf);

    k_aggr<<<NBUCK, 256, 0, stream>>>(gcnt, ebuf, m, s, Wout, bout, out);
}

// Round 4
// 1743.319 us; speedup vs baseline: 1.0017x; 1.0017x over previous
//
#include <hip/hip_runtime.h>

// Problem constants (from reference setup_inputs)
#define N_NODES  200000
#define N_EDGES  6400000
#define NGRAPH   128
#define H        32

// Bucketed aggregation parameters (re-grained for occupancy, R4)
#define BNODES   256                      // dst nodes per bucket (8 bits)
#define NBUCK    782                      // ceil(200000/256); last bucket has 64 nodes
#define P_BLOCKS 512                      // partition blocks
#define EPB      12500                    // edges per partition block (512*12500 = 6.4M)

// ---------------------------------------------------------------------------
// K0: h_global_graph = relu(x_global @ W_global + b_global)   [128, 32]
// ---------------------------------------------------------------------------
__global__ void k_global_enc(const float* __restrict__ xg,
                             const float* __restrict__ Wg,
                             const float* __restrict__ bg,
                             float* __restrict__ hg) {
    int tid = blockIdx.x * blockDim.x + threadIdx.x;
    if (tid >= NGRAPH * H) return;
    int b = tid >> 5, t = tid & 31;
    float acc = bg[t];
#pragma unroll
    for (int k = 0; k < 8; ++k)
        acc = fmaf(xg[b * 8 + k], Wg[k * H + t], acc);
    hg[tid] = fmaxf(acc, 0.f);
}

// ---------------------------------------------------------------------------
// K1: per-node encoder. 32 threads per node.
// m[n] = relu(h0 @ W_msg + b_msg)   (per-source message == self-loop msg)
// s[n] = h0 @ W_self + b_self       (pre-relu self path)
// ---------------------------------------------------------------------------
__global__ void k_node_enc(const float* __restrict__ xl,
                           const int*   __restrict__ batch,
                           const float* __restrict__ hg,
                           const float* __restrict__ Wl,   const float* __restrict__ bl,
                           const float* __restrict__ Wmix, const float* __restrict__ bmix,
                           const float* __restrict__ Wmsg, const float* __restrict__ bmsg,
                           const float* __restrict__ Wself,const float* __restrict__ bself,
                           float* __restrict__ m, float* __restrict__ s) {
    __shared__ float hcat[8][96];
    __shared__ float h0s[8][32];

    int tid   = threadIdx.x;
    int local = tid >> 5;
    int t     = tid & 31;
    int n     = blockIdx.x * 8 + local;   // 25000 blocks * 8 == 200000 exactly

    float hl = bl[t];
#pragma unroll
    for (int k = 0; k < 16; ++k)
        hl = fmaf(xl[n * 16 + k], Wl[k * H + t], hl);
    hl = fmaxf(hl, 0.f);

    float hgv = hg[batch[n] * H + t];

    hcat[local][t]      = hl;
    hcat[local][32 + t] = hgv;
    hcat[local][64 + t] = hl * hgv;
    __syncthreads();

    float h0 = bmix[t];
#pragma unroll
    for (int k = 0; k < 96; ++k)
        h0 = fmaf(hcat[local][k], Wmix[k * H + t], h0);
    h0 = fmaxf(h0, 0.f);
    h0s[local][t] = h0;
    __syncthreads();

    float mv = bmsg[t], sv = bself[t];
#pragma unroll
    for (int k = 0; k < 32; ++k) {
        float hv = h0s[local][k];
        mv = fmaf(hv, Wmsg[k * H + t], mv);
        sv = fmaf(hv, Wself[k * H + t], sv);
    }
    m[n * H + t] = fmaxf(mv, 0.f);
    s[n * H + t] = sv;
}

// ---------------------------------------------------------------------------
// Partition pass 1: per-(block,bucket) histogram.  gcnt[bucket*P_BLOCKS + blk]
// ---------------------------------------------------------------------------
__global__ void k_pcount(const int* __restrict__ ei, int* __restrict__ gcnt) {
    __shared__ int cnt[NBUCK];
    int t = threadIdx.x, blk = blockIdx.x;
    for (int i = t; i < NBUCK; i += 256) cnt[i] = 0;
    __syncthreads();
    int e1 = (blk + 1) * EPB;
    for (int e = blk * EPB + t; e < e1; e += 256)
        atomicAdd(&cnt[ei[N_EDGES + e] >> 8], 1);
    __syncthreads();
    for (int i = t; i < NBUCK; i += 256)
        gcnt[i * P_BLOCKS + blk] = cnt[i];
}

// ---------------------------------------------------------------------------
// Scan of gcnt (NBUCK rows of P_BLOCKS, bucket-major) -> exclusive offsets
// ---------------------------------------------------------------------------
__global__ void k_blocksum_g(const int* __restrict__ gcnt, int* __restrict__ bsum) {
    int b = blockIdx.x, t = threadIdx.x;   // 512 threads
    int v = gcnt[b * P_BLOCKS + t];
#pragma unroll
    for (int off = 32; off >= 1; off >>= 1)
        v += __shfl_down(v, off, 64);
    __shared__ int w8[8];
    if ((t & 63) == 0) w8[t >> 6] = v;
    __syncthreads();
    if (t == 0) {
        int acc = 0;
#pragma unroll
        for (int i = 0; i < 8; ++i) acc += w8[i];
        bsum[b] = acc;
    }
}

__global__ void k_scan_bsums_g(const int* __restrict__ bsum, int* __restrict__ boff) {
    __shared__ int sd[1024];
    int t = threadIdx.x;
    sd[t] = (t < NBUCK) ? bsum[t] : 0;
    __syncthreads();
#pragma unroll
    for (int off = 1; off < 1024; off <<= 1) {
        int v = (t >= off) ? sd[t - off] : 0;
        __syncthreads();
        sd[t] += v;
        __syncthreads();
    }
    if (t < NBUCK) boff[t] = (t == 0) ? 0 : sd[t - 1];
}

// in-place: gcnt -> exclusive global offset of each (bucket, block) region
__global__ void k_make_cursor_g(int* __restrict__ gcnt, const int* __restrict__ boff) {
    __shared__ int sd[P_BLOCKS];
    int b = blockIdx.x, t = threadIdx.x, i = b * P_BLOCKS + t;  // 512 threads
    int c = gcnt[i];
    sd[t] = c;
    __syncthreads();
#pragma unroll
    for (int off = 1; off < P_BLOCKS; off <<= 1) {
        int v = (t >= off) ? sd[t - off] : 0;
        __syncthreads();
        sd[t] += v;
        __syncthreads();
    }
    gcnt[i] = boff[b] + sd[t] - c;
}

// ---------------------------------------------------------------------------
// Partition pass 2: scatter packed edges into bucket-grouped ebuf.
// Each (block,bucket) owns a private contiguous ~16-entry (64B) region.
// ---------------------------------------------------------------------------
__global__ void k_pscatter(const int* __restrict__ ei, const int* __restrict__ goff,
                           unsigned int* __restrict__ ebuf) {
    __shared__ int cur[NBUCK];
    int t = threadIdx.x, blk = blockIdx.x;
    for (int i = t; i < NBUCK; i += 256) cur[i] = goff[i * P_BLOCKS + blk];
    __syncthreads();
    int e1 = (blk + 1) * EPB;
    for (int e = blk * EPB + t; e < e1; e += 256) {
        unsigned src = (unsigned)ei[e];           // < 2^18
        int dst = ei[N_EDGES + e];
        int pos = atomicAdd(&cur[dst >> 8], 1);
        ebuf[pos] = (src << 8) | (unsigned)(dst & 255);
    }
}

// ---------------------------------------------------------------------------
// K-aggr: one block (512 thr) per bucket. 32 KB LDS accumulator [256 x 32].
// 16 groups of 32 lanes: unroll-8 gather chains of m[src] (128B coalesced,
// LLC-resident), ds_add_f32 into acc (bank-conflict-free). Fused final head.
// ---------------------------------------------------------------------------
__global__ __launch_bounds__(512) void k_aggr(
        const int* __restrict__ goff,
        const unsigned int* __restrict__ ebuf,
        const float* __restrict__ m, const float* __restrict__ s,
        const float* __restrict__ Wout, const float* __restrict__ bout,
        float* __restrict__ out) {
    __shared__ float acc[BNODES * H];   // 32 KiB
    int t   = threadIdx.x & 31;
    int wid = threadIdx.x >> 5;         // 16 gather groups
    int b   = blockIdx.x;

    for (int i = threadIdx.x; i < BNODES * H; i += 512) acc[i] = 0.f;
    __syncthreads();

    int start = goff[b * P_BLOCKS];
    int end   = (b == NBUCK - 1) ? N_EDGES : goff[(b + 1) * P_BLOCKS];

    // unroll-8 independent gather chains per 32-lane group
    int j = start + wid;
    for (; j + 112 < end; j += 128) {
        unsigned p0 = ebuf[j];
        unsigned p1 = ebuf[j + 16];
        unsigned p2 = ebuf[j + 32];
        unsigned p3 = ebuf[j + 48];
        unsigned p4 = ebuf[j + 64];
        unsigned p5 = ebuf[j + 80];
        unsigned p6 = ebuf[j + 96];
        unsigned p7 = ebuf[j + 112];
        float v0 = m[(p0 >> 8) * H + t];
        float v1 = m[(p1 >> 8) * H + t];
        float v2 = m[(p2 >> 8) * H + t];
        float v3 = m[(p3 >> 8) * H + t];
        float v4 = m[(p4 >> 8) * H + t];
        float v5 = m[(p5 >> 8) * H + t];
        float v6 = m[(p6 >> 8) * H + t];
        float v7 = m[(p7 >> 8) * H + t];
        atomicAdd(&acc[(p0 & 255) * H + t], v0);
        atomicAdd(&acc[(p1 & 255) * H + t], v1);
        atomicAdd(&acc[(p2 & 255) * H + t], v2);
        atomicAdd(&acc[(p3 & 255) * H + t], v3);
        atomicAdd(&acc[(p4 & 255) * H + t], v4);
        atomicAdd(&acc[(p5 & 255) * H + t], v5);
        atomicAdd(&acc[(p6 & 255) * H + t], v6);
        atomicAdd(&acc[(p7 & 255) * H + t], v7);
    }
    for (; j < end; j += 16) {
        unsigned p = ebuf[j];
        atomicAdd(&acc[(p & 255) * H + t], m[(p >> 8) * H + t]);
    }
    __syncthreads();

    // fused final: h = relu(acc + m_self + s), 2-class head
    int nbase = b * BNODES;
    for (int nn = wid; nn < BNODES; nn += 16) {
        int n = nbase + nn;
        if (n < N_NODES) {
            int i = n * H + t;
            float h = fmaxf(acc[nn * H + t] + m[i] + s[i], 0.f);
            float p0 = h * Wout[t * 2 + 0];
            float p1 = h * Wout[t * 2 + 1];
#pragma unroll
            for (int off = 16; off >= 1; off >>= 1) {
                p0 += __shfl_down(p0, off, 32);
                p1 += __shfl_down(p1, off, 32);
            }
            if (t == 0) {
                out[n * 2 + 0] = p0 + bout[0];
                out[n * 2 + 1] = p1 + bout[1];
            }
        }
    }
}

// ---------------------------------------------------------------------------
extern "C" void kernel_launch(void* const* d_in, const int* in_sizes, int n_in,
                              void* d_out, int out_size, void* d_ws, size_t ws_size,
                              hipStream_t stream) {
    const float* xl    = (const float*)d_in[0];
    const float* xg    = (const float*)d_in[1];
    const int*   batch = (const int*)  d_in[2];
    const int*   ei    = (const int*)  d_in[3];
    const float* Wl    = (const float*)d_in[4];
    const float* bl    = (const float*)d_in[5];
    const float* Wg    = (const float*)d_in[6];
    const float* bg    = (const float*)d_in[7];
    const float* Wmix  = (const float*)d_in[8];
    const float* bmix  = (const float*)d_in[9];
    const float* Wmsg  = (const float*)d_in[10];
    const float* bmsg  = (const float*)d_in[11];
    const float* Wself = (const float*)d_in[12];
    const float* bself = (const float*)d_in[13];
    const float* Wout  = (const float*)d_in[14];
    const float* bout  = (const float*)d_in[15];
    float* out = (float*)d_out;

    // Workspace layout:
    //   hg   [128*32]          f32
    //   m    [N*32]            f32
    //   s    [N*32]            f32
    //   gcnt [NBUCK*P_BLOCKS]  i32   (becomes region offsets in place)
    //   bsum [NBUCK]           i32
    //   boff [NBUCK]           i32
    //   ebuf [E]               u32   (packed (src<<8)|dstLocal, bucket-grouped)
    float* hg   = (float*)d_ws;
    float* m    = hg + NGRAPH * H;
    float* s    = m + (size_t)N_NODES * H;
    int*   gcnt = (int*)(s + (size_t)N_NODES * H);
    int*   bsum = gcnt + (size_t)NBUCK * P_BLOCKS;
    int*   boff = bsum + NBUCK;
    unsigned int* ebuf = (unsigned int*)(boff + NBUCK);

    k_global_enc<<<(NGRAPH * H + 255) / 256, 256, 0, stream>>>(xg, Wg, bg, hg);

    k_node_enc<<<N_NODES / 8, 256, 0, stream>>>(xl, batch, hg,
                                                Wl, bl, Wmix, bmix,
                                                Wmsg, bmsg, Wself, bself,
                                                m, s);

    k_pcount<<<P_BLOCKS, 256, 0, stream>>>(ei, gcnt);
    k_blocksum_g<<<NBUCK, P_BLOCKS, 0, stream>>>(gcnt, bsum);
    k_scan_bsums_g<<<1, 1024, 0, stream>>>(bsum, boff);
    k_make_cursor_g<<<NBUCK, P_BLOCKS, 0, stream>>>(gcnt, boff);
    k_pscatter<<<P_BLOCKS, 256, 0, stream>>>(ei, gcnt, ebuf);

    k_aggr<<<NBUCK, 512, 0, stream>>>(gcnt, ebuf, m, s, Wout, bout, out);
}